// Round 1
// baseline (633.793 us; speedup 1.0000x reference)
//
#include <hip/hip_runtime.h>
#include <stdint.h>

#define T_TOK 4096
#define DDIM  1024
#define HDIM  4096
#define NEXP  8
#define MAXTILES 72   // ceil(8192/128) + 8 experts of padding

typedef short s16x8  __attribute__((ext_vector_type(8)));
typedef float f32x4t __attribute__((ext_vector_type(4)));

__device__ __forceinline__ unsigned short f2b(float f){
  unsigned int u = __float_as_uint(f);
  u += 0x7fffu + ((u >> 16) & 1u);   // round-to-nearest-even
  return (unsigned short)(u >> 16);
}

// ---------------- gate: logits -> softmax -> top2 ----------------
__global__ void gate_kernel(const float* __restrict__ x, const float* __restrict__ Wg,
                            const float* __restrict__ bg,
                            int* __restrict__ topk_e, float* __restrict__ topk_w){
  const int t = blockIdx.x;
  const int lane = threadIdx.x;          // 64 threads = 1 wave
  const float* xr = x + (size_t)t * DDIM;
  float acc[NEXP];
  #pragma unroll
  for (int e = 0; e < NEXP; ++e) acc[e] = 0.f;
  #pragma unroll 4
  for (int it = 0; it < DDIM/64; ++it){
    int i = it*64 + lane;
    float xi = xr[i];
    const float4* wr = (const float4*)(Wg + (size_t)i * NEXP);
    float4 w0 = wr[0], w1 = wr[1];
    acc[0] += xi*w0.x; acc[1] += xi*w0.y; acc[2] += xi*w0.z; acc[3] += xi*w0.w;
    acc[4] += xi*w1.x; acc[5] += xi*w1.y; acc[6] += xi*w1.z; acc[7] += xi*w1.w;
  }
  #pragma unroll
  for (int e = 0; e < NEXP; ++e){
    float v = acc[e];
    #pragma unroll
    for (int off = 32; off > 0; off >>= 1) v += __shfl_xor(v, off, 64);
    acc[e] = v;
  }
  if (lane == 0){
    float l[NEXP], m = -1e30f;
    #pragma unroll
    for (int e = 0; e < NEXP; ++e){ l[e] = acc[e] + bg[e]; m = fmaxf(m, l[e]); }
    float p[NEXP], s = 0.f;
    #pragma unroll
    for (int e = 0; e < NEXP; ++e){ p[e] = expf(l[e] - m); s += p[e]; }
    float inv = 1.f / s;
    int a1 = 0; float v1 = -1.f;
    #pragma unroll
    for (int e = 0; e < NEXP; ++e){ p[e] *= inv; if (p[e] > v1){ v1 = p[e]; a1 = e; } }
    int a2 = -1; float v2 = -1.f;
    #pragma unroll
    for (int e = 0; e < NEXP; ++e){ if (e == a1) continue; if (p[e] > v2){ v2 = p[e]; a2 = e; } }
    topk_e[2*t]   = a1; topk_w[2*t]   = v1;
    topk_e[2*t+1] = a2; topk_w[2*t+1] = v2;
  }
}

// ---------------- routing: per-expert ordered compaction ----------------
__global__ void route_count(const int* __restrict__ topk_e, const float* __restrict__ topk_w,
                            int* __restrict__ expertList, float* __restrict__ pairW,
                            int* __restrict__ counts){
  const int e = blockIdx.x;      // 8 blocks
  const int tid = threadIdx.x;   // 256 threads
  __shared__ int pfx[256];
  __shared__ int base_s;
  if (tid == 0) base_s = 0;
  __syncthreads();
  for (int c = 0; c < T_TOK/256; ++c){
    int t = c*256 + tid;
    int e0 = topk_e[2*t], e1 = topk_e[2*t+1];
    int sel = 0; float w = 0.f;
    if (e0 == e){ sel = 1; w = topk_w[2*t]; }
    else if (e1 == e){ sel = 1; w = topk_w[2*t+1]; }
    pfx[tid] = sel;
    __syncthreads();
    for (int off = 1; off < 256; off <<= 1){
      int v = (tid >= off) ? pfx[tid - off] : 0;
      __syncthreads();
      pfx[tid] += v;
      __syncthreads();
    }
    if (sel){
      int pos = base_s + pfx[tid] - 1;
      expertList[e*T_TOK + pos] = t;
      pairW[e*T_TOK + pos] = w;
    }
    __syncthreads();
    if (tid == 0) base_s += pfx[255];
    __syncthreads();
  }
  if (tid == 0) counts[e] = base_s;
}

__global__ void plan_kernel(const int* __restrict__ counts, int* __restrict__ nTiles,
                            int* __restrict__ tileExpert, int* __restrict__ tileStart){
  if (blockIdx.x != 0 || threadIdx.x != 0) return;
  int nt = 0;
  for (int e = 0; e < NEXP; ++e){
    int c = counts[e];
    int tcount = (c + 127) >> 7;
    for (int i = 0; i < tcount; ++i){ tileExpert[nt] = e; tileStart[nt] = i*128; ++nt; }
  }
  *nTiles = nt;
}

// ---------------- grouped GEMM: 128x128 tile, BK=32, 4 waves ----------------
template<int LAYER>
__global__ __launch_bounds__(256)
void moe_gemm(const float* __restrict__ Xf,             // layer1 A source (gathered)
              const unsigned short* __restrict__ Ain,   // layer2 A source (Hact bf16)
              const float* __restrict__ W,              // W1 or W2 (fp32, [E][K][N])
              const float* __restrict__ bias,           // b1 or b2
              const int* __restrict__ nTilesPtr,
              const int* __restrict__ tileExpert,
              const int* __restrict__ tileStart,
              const int* __restrict__ counts,
              const int* __restrict__ expertList,
              const float* __restrict__ pairW,
              unsigned short* __restrict__ Hout,        // layer1 output (bf16)
              float* __restrict__ out)                  // layer2 output (fp32, atomic)
{
  const int tile = blockIdx.x;
  if (tile >= *nTilesPtr) return;
  const int KD = (LAYER == 1) ? DDIM : HDIM;
  const int ND = (LAYER == 1) ? HDIM : DDIM;
  const int e   = tileExpert[tile];
  const int ts  = tileStart[tile];
  const int cnt = counts[e];
  const int n0  = blockIdx.y * 128;
  const int tid  = threadIdx.x;
  const int lane = tid & 63;
  const int wave = tid >> 6;
  const int wm = (wave >> 1) * 64;
  const int wn = (wave & 1) * 64;

  __shared__ __align__(16) unsigned short As[128][40];  // [m][k], pad to 40
  __shared__ __align__(16) unsigned short Bs[128][40];  // [n][k] (transposed)
  __shared__ int   tokenBuf[128];
  __shared__ float wBuf[128];

  if (tid < 128){
    int pos = ts + tid;
    int tok = -1; float w = 0.f;
    if (pos < cnt){ tok = expertList[e*T_TOK + pos]; w = pairW[e*T_TOK + pos]; }
    tokenBuf[tid] = tok; wBuf[tid] = w;
  }
  __syncthreads();

  f32x4t acc[4][4] = {};

  const int arow  = tid >> 1;
  const int ahalf = (tid & 1) * 16;
  const int brow  = tid >> 3;          // 0..31
  const int bc0   = (tid & 7) * 16;    // 0..112
  const float* Wbase = W + (size_t)e * KD * ND + n0 + bc0;
  const int tokA = tokenBuf[arow];

  for (int ko = 0; ko < KD; ko += 32){
    // ---- stage A (128 x 32 bf16) ----
    if (LAYER == 1){
      alignas(16) unsigned short tmp[16];
      if (tokA >= 0){
        const float4* src = (const float4*)(Xf + (size_t)tokA*DDIM + ko + ahalf);
        #pragma unroll
        for (int q = 0; q < 4; ++q){
          float4 v = src[q];
          tmp[q*4+0] = f2b(v.x); tmp[q*4+1] = f2b(v.y);
          tmp[q*4+2] = f2b(v.z); tmp[q*4+3] = f2b(v.w);
        }
      } else {
        #pragma unroll
        for (int q = 0; q < 16; ++q) tmp[q] = 0;
      }
      *(s16x8*)&As[arow][ahalf]     = *(const s16x8*)tmp;
      *(s16x8*)&As[arow][ahalf + 8] = *(const s16x8*)(tmp + 8);
    } else {
      const s16x8* src = (const s16x8*)(Ain + (size_t)(tile*128 + arow)*HDIM + ko + ahalf);
      *(s16x8*)&As[arow][ahalf]     = src[0];
      *(s16x8*)&As[arow][ahalf + 8] = src[1];
    }
    // ---- stage B (32 x 128 fp32 -> bf16, transposed to [n][k]) ----
    {
      const float4* src = (const float4*)(Wbase + (size_t)(ko + brow) * ND);
      alignas(16) unsigned short tb[16];
      #pragma unroll
      for (int q = 0; q < 4; ++q){
        float4 v = src[q];
        tb[q*4+0] = f2b(v.x); tb[q*4+1] = f2b(v.y);
        tb[q*4+2] = f2b(v.z); tb[q*4+3] = f2b(v.w);
      }
      #pragma unroll
      for (int j = 0; j < 16; ++j) Bs[bc0 + j][brow] = tb[j];
    }
    __syncthreads();
    // ---- MFMA ----
    const int kg = (lane >> 4) * 8;
    s16x8 af[4], bf[4];
    #pragma unroll
    for (int mf = 0; mf < 4; ++mf) af[mf] = *(const s16x8*)&As[wm + mf*16 + (lane & 15)][kg];
    #pragma unroll
    for (int nf = 0; nf < 4; ++nf) bf[nf] = *(const s16x8*)&Bs[wn + nf*16 + (lane & 15)][kg];
    #pragma unroll
    for (int mf = 0; mf < 4; ++mf)
      #pragma unroll
      for (int nf = 0; nf < 4; ++nf)
        acc[mf][nf] = __builtin_amdgcn_mfma_f32_16x16x32_bf16(af[mf], bf[nf], acc[mf][nf], 0, 0, 0);
    __syncthreads();
  }

  // ---- epilogue ----
  const int rb = wm + ((lane >> 4) * 4);
  const int cb = wn + (lane & 15);
  if (LAYER == 1){
    #pragma unroll
    for (int mf = 0; mf < 4; ++mf){
      #pragma unroll
      for (int nf = 0; nf < 4; ++nf){
        int c = cb + nf*16;
        float b = bias[e*HDIM + n0 + c];
        #pragma unroll
        for (int j = 0; j < 4; ++j){
          int r = rb + mf*16 + j;
          float v = acc[mf][nf][j] + b;
          v = fmaxf(v, 0.f);
          Hout[(size_t)(tile*128 + r)*HDIM + n0 + c] = f2b(v);
        }
      }
    }
  } else {
    #pragma unroll
    for (int mf = 0; mf < 4; ++mf){
      #pragma unroll
      for (int j = 0; j < 4; ++j){
        int r = rb + mf*16 + j;
        if (ts + r < cnt){
          int tok = tokenBuf[r];
          float w = wBuf[r];
          #pragma unroll
          for (int nf = 0; nf < 4; ++nf){
            int c = cb + nf*16;
            float v = w * (acc[mf][nf][j] + bias[e*DDIM + n0 + c]);
            atomicAdd(out + (size_t)tok*DDIM + n0 + c, v);
          }
        }
      }
    }
  }
}

extern "C" void kernel_launch(void* const* d_in, const int* in_sizes, int n_in,
                              void* d_out, int out_size, void* d_ws, size_t ws_size,
                              hipStream_t stream){
  const float* x  = (const float*)d_in[0];
  const float* Wg = (const float*)d_in[1];
  const float* bg = (const float*)d_in[2];
  const float* W1 = (const float*)d_in[3];
  const float* b1 = (const float*)d_in[4];
  const float* W2 = (const float*)d_in[5];
  const float* b2 = (const float*)d_in[6];
  float* out = (float*)d_out;

  char* p = (char*)d_ws;
  int*   topk_e     = (int*)p;   p += (size_t)T_TOK*2*sizeof(int);
  float* topk_w     = (float*)p; p += (size_t)T_TOK*2*sizeof(float);
  int*   counts     = (int*)p;   p += 8*sizeof(int);
  int*   nTiles     = (int*)p;   p += 8*sizeof(int);
  int*   tileExpert = (int*)p;   p += 128*sizeof(int);
  int*   tileStart  = (int*)p;   p += 128*sizeof(int);
  int*   expertList = (int*)p;   p += (size_t)NEXP*T_TOK*sizeof(int);
  float* pairW      = (float*)p; p += (size_t)NEXP*T_TOK*sizeof(float);
  p = (char*)(((uintptr_t)p + 255) & ~(uintptr_t)255);
  unsigned short* Hact = (unsigned short*)p;   // [MAXTILES*128][HDIM] bf16 ~ 75.5 MB

  hipMemsetAsync(d_out, 0, (size_t)T_TOK*DDIM*sizeof(float), stream);
  gate_kernel<<<T_TOK, 64, 0, stream>>>(x, Wg, bg, topk_e, topk_w);
  route_count<<<NEXP, 256, 0, stream>>>(topk_e, topk_w, expertList, pairW, counts);
  plan_kernel<<<1, 1, 0, stream>>>(counts, nTiles, tileExpert, tileStart);
  moe_gemm<1><<<dim3(MAXTILES, HDIM/128), 256, 0, stream>>>(
      x, nullptr, W1, b1, nTiles, tileExpert, tileStart, counts, expertList, pairW, Hact, nullptr);
  moe_gemm<2><<<dim3(MAXTILES, DDIM/128), 256, 0, stream>>>(
      nullptr, Hact, W2, b2, nTiles, tileExpert, tileStart, counts, expertList, pairW, nullptr, out);
}

// Round 2
// 464.285 us; speedup vs baseline: 1.3651x; 1.3651x over previous
//
#include <hip/hip_runtime.h>
#include <stdint.h>

#define T_TOK 4096
#define DDIM  1024
#define HDIM  4096
#define NEXP  8
#define MAXTILES 72

typedef short s16x8  __attribute__((ext_vector_type(8)));
typedef short s16x4  __attribute__((ext_vector_type(4)));
typedef float f32x4t __attribute__((ext_vector_type(4)));

#define GLOAD16(gp, lp) __builtin_amdgcn_global_load_lds( \
    (const __attribute__((address_space(1))) unsigned int*)(gp), \
    (__attribute__((address_space(3))) unsigned int*)(lp), 16, 0, 0)

__device__ __forceinline__ unsigned short f2b(float f){
  unsigned int u = __float_as_uint(f);
  u += 0x7fffu + ((u >> 16) & 1u);   // RNE
  return (unsigned short)(u >> 16);
}

// ---------------- gate: logits -> softmax -> top2 ----------------
__global__ void gate_kernel(const float* __restrict__ x, const float* __restrict__ Wg,
                            const float* __restrict__ bg,
                            int* __restrict__ topk_e, float* __restrict__ topk_w){
  const int t = blockIdx.x;
  const int lane = threadIdx.x;          // 64 threads = 1 wave
  const float* xr = x + (size_t)t * DDIM;
  float acc[NEXP];
  #pragma unroll
  for (int e = 0; e < NEXP; ++e) acc[e] = 0.f;
  #pragma unroll 4
  for (int it = 0; it < DDIM/64; ++it){
    int i = it*64 + lane;
    float xi = xr[i];
    const float4* wr = (const float4*)(Wg + (size_t)i * NEXP);
    float4 w0 = wr[0], w1 = wr[1];
    acc[0] += xi*w0.x; acc[1] += xi*w0.y; acc[2] += xi*w0.z; acc[3] += xi*w0.w;
    acc[4] += xi*w1.x; acc[5] += xi*w1.y; acc[6] += xi*w1.z; acc[7] += xi*w1.w;
  }
  #pragma unroll
  for (int e = 0; e < NEXP; ++e){
    float v = acc[e];
    #pragma unroll
    for (int off = 32; off > 0; off >>= 1) v += __shfl_xor(v, off, 64);
    acc[e] = v;
  }
  if (lane == 0){
    float l[NEXP], m = -1e30f;
    #pragma unroll
    for (int e = 0; e < NEXP; ++e){ l[e] = acc[e] + bg[e]; m = fmaxf(m, l[e]); }
    float p[NEXP], s = 0.f;
    #pragma unroll
    for (int e = 0; e < NEXP; ++e){ p[e] = expf(l[e] - m); s += p[e]; }
    float inv = 1.f / s;
    int a1 = 0; float v1 = -1.f;
    #pragma unroll
    for (int e = 0; e < NEXP; ++e){ p[e] *= inv; if (p[e] > v1){ v1 = p[e]; a1 = e; } }
    int a2 = -1; float v2 = -1.f;
    #pragma unroll
    for (int e = 0; e < NEXP; ++e){ if (e == a1) continue; if (p[e] > v2){ v2 = p[e]; a2 = e; } }
    topk_e[2*t]   = a1; topk_w[2*t]   = v1;
    topk_e[2*t+1] = a2; topk_w[2*t+1] = v2;
  }
}

// ---------------- routing: per-expert ordered compaction ----------------
__global__ void route_count(const int* __restrict__ topk_e, const float* __restrict__ topk_w,
                            int* __restrict__ expertList, float* __restrict__ pairW,
                            int* __restrict__ counts){
  const int e = blockIdx.x;
  const int tid = threadIdx.x;   // 256
  __shared__ int pfx[256];
  __shared__ int base_s;
  if (tid == 0) base_s = 0;
  __syncthreads();
  for (int c = 0; c < T_TOK/256; ++c){
    int t = c*256 + tid;
    int e0 = topk_e[2*t], e1 = topk_e[2*t+1];
    int sel = 0; float w = 0.f;
    if (e0 == e){ sel = 1; w = topk_w[2*t]; }
    else if (e1 == e){ sel = 1; w = topk_w[2*t+1]; }
    pfx[tid] = sel;
    __syncthreads();
    for (int off = 1; off < 256; off <<= 1){
      int v = (tid >= off) ? pfx[tid - off] : 0;
      __syncthreads();
      pfx[tid] += v;
      __syncthreads();
    }
    if (sel){
      int pos = base_s + pfx[tid] - 1;
      expertList[e*T_TOK + pos] = t;
      pairW[e*T_TOK + pos] = w;
    }
    __syncthreads();
    if (tid == 0) base_s += pfx[255];
    __syncthreads();
  }
  if (tid == 0) counts[e] = base_s;
}

__global__ void plan_kernel(const int* __restrict__ counts, int* __restrict__ nTiles,
                            int* __restrict__ tileExpert, int* __restrict__ tileStart){
  if (blockIdx.x != 0 || threadIdx.x != 0) return;
  int nt = 0;
  for (int e = 0; e < NEXP; ++e){
    int c = counts[e];
    int tcount = (c + 127) >> 7;
    for (int i = 0; i < tcount; ++i){ tileExpert[nt] = e; tileStart[nt] = i*128; ++nt; }
  }
  *nTiles = nt;
}

// ---------------- pre-pass: x fp32 -> bf16 ----------------
__global__ void conv_x(const float* __restrict__ x, unsigned short* __restrict__ xb){
  int i = (blockIdx.x*256 + threadIdx.x)*4;
  float4 v = *(const float4*)(x + i);
  s16x4 o;
  o[0] = (short)f2b(v.x); o[1] = (short)f2b(v.y);
  o[2] = (short)f2b(v.z); o[3] = (short)f2b(v.w);
  *(s16x4*)(xb + i) = o;
}

// ---------------- pre-pass: W [E][K][N] fp32 -> Wt [E][N][K] bf16 ----------------
__global__ __launch_bounds__(256)
void transpose_w(const float* __restrict__ W, unsigned short* __restrict__ Wt,
                 int K, int N){
  const int e = blockIdx.z;
  const float* Wb = W + (size_t)e*K*N;
  unsigned short* Wtb = Wt + (size_t)e*K*N;
  const int n0 = blockIdx.x*64, k0 = blockIdx.y*64;
  __shared__ unsigned short t[64][72];   // [n][k], padded
  const int r  = threadIdx.x >> 4;        // 0..15
  const int c4 = (threadIdx.x & 15) * 4;  // 0..60
  #pragma unroll
  for (int i = 0; i < 4; ++i){
    int k = r + i*16;
    float4 v = *(const float4*)(Wb + (size_t)(k0+k)*N + n0 + c4);
    t[c4+0][k] = f2b(v.x); t[c4+1][k] = f2b(v.y);
    t[c4+2][k] = f2b(v.z); t[c4+3][k] = f2b(v.w);
  }
  __syncthreads();
  const int kk = (threadIdx.x & 7) * 8;
  #pragma unroll
  for (int i = 0; i < 2; ++i){
    int n = (threadIdx.x >> 3) + i*32;
    s16x8 v;
    #pragma unroll
    for (int j = 0; j < 8; ++j) v[j] = (short)t[n][kk+j];
    *(s16x8*)(Wtb + (size_t)(n0+n)*K + k0 + kk) = v;
  }
}

// ---------------- grouped GEMM: 128x128 tile, BK=64, 4 waves, global_load_lds ----------------
template<int LAYER>
__global__ __launch_bounds__(256)
void moe_gemm(const unsigned short* __restrict__ Abf,  // L1: xb [T][D]; L2: Hact [rows][H]
              const unsigned short* __restrict__ Wt,   // bf16 [E][ND][KD] (pre-transposed)
              const float* __restrict__ bias,
              const int* __restrict__ nTilesPtr,
              const int* __restrict__ tileExpert,
              const int* __restrict__ tileStart,
              const int* __restrict__ counts,
              const int* __restrict__ expertList,
              const float* __restrict__ pairW,
              unsigned short* __restrict__ Hout,
              float* __restrict__ out)
{
  const int tile = blockIdx.x;
  if (tile >= *nTilesPtr) return;
  constexpr int KD = (LAYER == 1) ? DDIM : HDIM;
  constexpr int ND = (LAYER == 1) ? HDIM : DDIM;
  const int e   = tileExpert[tile];
  const int ts  = tileStart[tile];
  const int cnt = counts[e];
  const int n0  = blockIdx.y * 128;
  const int tid  = threadIdx.x;
  const int lane = tid & 63;
  const int wave = tid >> 6;
  const int wm = (wave >> 1) * 64;
  const int wn = (wave & 1) * 64;

  __shared__ __align__(16) unsigned short As[128][64];
  __shared__ __align__(16) unsigned short Bs[128][64];
  __shared__ int   tokenBuf[128];
  __shared__ float wBuf[128];

  if (tid < 128){
    int pos = ts + tid;
    int tok = 0; float w = 0.f;                 // pad rows read token 0 (finite garbage, discarded)
    if (pos < cnt){ tok = expertList[e*T_TOK + pos]; w = pairW[e*T_TOK + pos]; }
    tokenBuf[tid] = tok; wBuf[tid] = w;
  }
  __syncthreads();

  // staging addressing: 4 groups x (256 threads x 16B) = 16 KB per tile
  const int rsub = tid >> 3;          // 0..31
  const int koff = (tid & 7) * 8;     // element offset in 64-wide row
  const unsigned short* gA[4];
  const unsigned short* gB[4];
  #pragma unroll
  for (int g = 0; g < 4; ++g){
    const int row = g*32 + rsub;
    if (LAYER == 1) gA[g] = Abf + (size_t)tokenBuf[row]*DDIM + koff;
    else            gA[g] = Abf + (size_t)(tile*128 + row)*HDIM + koff;
    gB[g] = Wt + ((size_t)e*ND + n0 + row)*KD + koff;
  }
  unsigned short* ldsA = &As[0][0] + wave*512;
  unsigned short* ldsB = &Bs[0][0] + wave*512;

  f32x4t acc[4][4] = {};
  const int fr = lane & 15;
  const int fq = lane >> 4;

  for (int ko = 0; ko < KD; ko += 64){
    #pragma unroll
    for (int g = 0; g < 4; ++g){
      GLOAD16(gA[g] + ko, ldsA + g*2048);
      GLOAD16(gB[g] + ko, ldsB + g*2048);
    }
    __syncthreads();   // compiler drains vmcnt before s_barrier
    #pragma unroll
    for (int ks = 0; ks < 2; ++ks){
      s16x8 af[4], bf[4];
      #pragma unroll
      for (int mf = 0; mf < 4; ++mf) af[mf] = *(const s16x8*)&As[wm + mf*16 + fr][ks*32 + fq*8];
      #pragma unroll
      for (int nf = 0; nf < 4; ++nf) bf[nf] = *(const s16x8*)&Bs[wn + nf*16 + fr][ks*32 + fq*8];
      #pragma unroll
      for (int mf = 0; mf < 4; ++mf)
        #pragma unroll
        for (int nf = 0; nf < 4; ++nf)
          acc[mf][nf] = __builtin_amdgcn_mfma_f32_16x16x32_bf16(af[mf], bf[nf], acc[mf][nf], 0, 0, 0);
    }
    __syncthreads();
  }

  // ---- epilogue ----
  const int rb = wm + fq*4;
  const int cb = wn + fr;
  if (LAYER == 1){
    #pragma unroll
    for (int mf = 0; mf < 4; ++mf){
      #pragma unroll
      for (int nf = 0; nf < 4; ++nf){
        int c = cb + nf*16;
        float b = bias[e*HDIM + n0 + c];
        #pragma unroll
        for (int j = 0; j < 4; ++j){
          int r = rb + mf*16 + j;
          float v = fmaxf(acc[mf][nf][j] + b, 0.f);
          Hout[(size_t)(tile*128 + r)*HDIM + n0 + c] = f2b(v);
        }
      }
    }
  } else {
    #pragma unroll
    for (int mf = 0; mf < 4; ++mf){
      #pragma unroll
      for (int j = 0; j < 4; ++j){
        int r = rb + mf*16 + j;
        if (ts + r < cnt){
          int tok = tokenBuf[r];
          float w = wBuf[r];
          #pragma unroll
          for (int nf = 0; nf < 4; ++nf){
            int c = cb + nf*16;
            float v = w * (acc[mf][nf][j] + bias[e*DDIM + n0 + c]);
            atomicAdd(out + (size_t)tok*DDIM + n0 + c, v);
          }
        }
      }
    }
  }
}

extern "C" void kernel_launch(void* const* d_in, const int* in_sizes, int n_in,
                              void* d_out, int out_size, void* d_ws, size_t ws_size,
                              hipStream_t stream){
  const float* x  = (const float*)d_in[0];
  const float* Wg = (const float*)d_in[1];
  const float* bg = (const float*)d_in[2];
  const float* W1 = (const float*)d_in[3];
  const float* b1 = (const float*)d_in[4];
  const float* W2 = (const float*)d_in[5];
  const float* b2 = (const float*)d_in[6];
  float* out = (float*)d_out;

  char* p = (char*)d_ws;
  int*   topk_e     = (int*)p;   p += (size_t)T_TOK*2*sizeof(int);
  float* topk_w     = (float*)p; p += (size_t)T_TOK*2*sizeof(float);
  int*   counts     = (int*)p;   p += 8*sizeof(int);
  int*   nTiles     = (int*)p;   p += 8*sizeof(int);
  int*   tileExpert = (int*)p;   p += 128*sizeof(int);
  int*   tileStart  = (int*)p;   p += 128*sizeof(int);
  int*   expertList = (int*)p;   p += (size_t)NEXP*T_TOK*sizeof(int);
  float* pairW      = (float*)p; p += (size_t)NEXP*T_TOK*sizeof(float);
  p = (char*)(((uintptr_t)p + 255) & ~(uintptr_t)255);
  unsigned short* xb = (unsigned short*)p;    // 8 MB
  p += (size_t)T_TOK*DDIM*sizeof(unsigned short);
  p = (char*)(((uintptr_t)p + 255) & ~(uintptr_t)255);
  unsigned short* Wtbuf = (unsigned short*)p; // 67 MB, shared by W1t then W2t
  p += (size_t)NEXP*DDIM*HDIM*sizeof(unsigned short);
  p = (char*)(((uintptr_t)p + 255) & ~(uintptr_t)255);
  unsigned short* Hact = (unsigned short*)p;  // 75.5 MB

  hipMemsetAsync(d_out, 0, (size_t)T_TOK*DDIM*sizeof(float), stream);
  gate_kernel<<<T_TOK, 64, 0, stream>>>(x, Wg, bg, topk_e, topk_w);
  route_count<<<NEXP, 256, 0, stream>>>(topk_e, topk_w, expertList, pairW, counts);
  plan_kernel<<<1, 1, 0, stream>>>(counts, nTiles, tileExpert, tileStart);
  conv_x<<<T_TOK*DDIM/1024, 256, 0, stream>>>(x, xb);

  // W1 [E][D][H] -> W1t [E][H][D]
  transpose_w<<<dim3(HDIM/64, DDIM/64, NEXP), 256, 0, stream>>>(W1, Wtbuf, DDIM, HDIM);
  moe_gemm<1><<<dim3(MAXTILES, HDIM/128), 256, 0, stream>>>(
      xb, Wtbuf, b1, nTiles, tileExpert, tileStart, counts, expertList, pairW, Hact, nullptr);

  // W2 [E][H][D] -> W2t [E][D][H] (reuses Wtbuf; GEMM1 has finished reading it)
  transpose_w<<<dim3(DDIM/64, HDIM/64, NEXP), 256, 0, stream>>>(W2, Wtbuf, HDIM, DDIM);
  moe_gemm<2><<<dim3(MAXTILES, DDIM/128), 256, 0, stream>>>(
      Hact, Wtbuf, b2, nTiles, tileExpert, tileStart, counts, expertList, pairW, nullptr, out);
}